// Round 20
// baseline (66.501 us; speedup 1.0000x reference)
//
#include <hip/hip_runtime.h>
#include <hip/hip_bf16.h>
#include <stdint.h>

#define B_ 4
#define N_ 2000
#define T_ 12
#define D_ 64
#define K_ 3
#define DEG_ 8
#define E_ (N_*DEG_)              // 16000
#define ROWS_ (B_*N_*T_)          // 96000
#define NT_ (N_*T_)               // 24000
#define V4PB_ (T_*D_/4)           // 192 4-channel groups per (node,b)
#define SLOTB_ 8                  // bytes per 4-channel group: f0..f3 e4m3 + p0..p3 e4m3
#define CHUNKB_ (64*SLOTB_)       // 512 B per (phase, node) chunk
#define LOG2E_ 1.4426950408889634f

typedef __attribute__((ext_vector_type(8))) short short8v;   // 8 bf16 = 4 VGPR
typedef __attribute__((ext_vector_type(4))) float f32x4;     // MFMA acc
typedef __attribute__((ext_vector_type(2))) float f32x2;     // fp8 cvt result

__device__ __forceinline__ uint32_t f32_to_bf16_bits(float x) {
    uint32_t u = __float_as_uint(x);
    return (u + 0x7FFFu + ((u >> 16) & 1u)) >> 16;   // RNE
}
__device__ __forceinline__ short8v cvt8(float4 lo, float4 hi) {
    short8v af;
    af[0] = (short)f32_to_bf16_bits(lo.x);
    af[1] = (short)f32_to_bf16_bits(lo.y);
    af[2] = (short)f32_to_bf16_bits(lo.z);
    af[3] = (short)f32_to_bf16_bits(lo.w);
    af[4] = (short)f32_to_bf16_bits(hi.x);
    af[5] = (short)f32_to_bf16_bits(hi.y);
    af[6] = (short)f32_to_bf16_bits(hi.z);
    af[7] = (short)f32_to_bf16_bits(hi.w);
    return af;
}

// ---------- Kernel 0 (prep): fragment-linear W table + bias ----------
// WBf[(tile*2+s)*64 + lane][e] = bf16 of W-col c = tile*16 + (lane&15),
// k = s*32 + (lane>>4)*8 + e; c<64 -> Wm[:,c], c>=64 -> log2e*(Wm@W1)[:,c-64]
// (W1 = W_attn[:64]; W2/b_attn cancel in the per-dst softmax; max-shift cancels
// so the logit half is pre-exponentiated downstream).
__global__ void prep_kernel(const float* __restrict__ Wm,
                            const float* __restrict__ Wa,
                            const float* __restrict__ bm,
                            uint16_t* __restrict__ WBf,
                            float* __restrict__ bpp) {
    const int blk  = blockIdx.x;          // 0..16
    const int lane = threadIdx.x;         // 64
    if (blk < 16) {
        const int tile = blk >> 1, s = blk & 1;
        const int r = lane & 15, q = lane >> 4;
        const int c = tile*16 + r;
        uint16_t o[8];
        #pragma unroll
        for (int e = 0; e < 8; ++e) {
            const int k = s*32 + q*8 + e;
            float v;
            if (c < 64) {
                v = Wm[k*64 + c];
            } else {
                v = 0.f;
                #pragma unroll
                for (int j = 0; j < 64; ++j) v += Wm[k*64 + j] * Wa[j*64 + (c - 64)];
                v *= LOG2E_;
            }
            o[e] = (uint16_t)f32_to_bf16_bits(v);
        }
        *(uint4*)(WBf + (size_t)(blk*64 + lane)*8) = *(const uint4*)o;
    } else {
        float s = 0.f;
        #pragma unroll
        for (int e = 0; e < 64; ++e) s += bm[e] * Wa[e*64 + lane];
        bpp[lane] = s * LOG2E_;
    }
}

// ---------- Kernel 1: MFMA GEMM [96000x64]@[64x128] -> pack (f fp8, p fp8) ----------
// R13 structure (measured ~11.3 µs). 8 B per 4-channel group:
// dword0 = f0..f3 e4m3, dword1 = p0..p3 e4m3; phase-major chunks of 512 B.
__launch_bounds__(256)
__global__ void mlp_mfma(const float* __restrict__ X,
                         const uint16_t* __restrict__ WBf,
                         const float* __restrict__ bm,
                         const float* __restrict__ bpp,
                         char* __restrict__ packed) {
    const int t    = threadIdx.x;
    const int wave = t >> 6, lane = t & 63;
    const int r    = lane & 15, q = lane >> 4;

    const int row0 = blockIdx.x*128 + wave*32;
    const int gR0  = row0 + r;            // row-tile 0
    const int gR1  = row0 + 16 + r;       // row-tile 1

    // X loads first (long latency), both row-tiles, both K-halves.
    const float* xp0 = X + (size_t)gR0*64 + q*8;
    const float* xp1 = X + (size_t)gR1*64 + q*8;
    const float4 a00 = *(const float4*)(xp0);
    const float4 a01 = *(const float4*)(xp0 + 4);
    const float4 a02 = *(const float4*)(xp0 + 32);
    const float4 a03 = *(const float4*)(xp0 + 36);
    const float4 a10 = *(const float4*)(xp1);
    const float4 a11 = *(const float4*)(xp1 + 4);
    const float4 a12 = *(const float4*)(xp1 + 32);
    const float4 a13 = *(const float4*)(xp1 + 36);

    // W fragments, fragment-linear: 16 contiguous 1-KB wave loads (L1-resident).
    short8v wfrag[8][2];
    #pragma unroll
    for (int tile = 0; tile < 8; ++tile)
        #pragma unroll
        for (int s = 0; s < 2; ++s)
            wfrag[tile][s] = *(const short8v*)(WBf + (size_t)((tile*2+s)*64 + lane)*8);

    f32x4 acc0[8], acc1[8];
    #pragma unroll
    for (int tile = 0; tile < 8; ++tile) {
        acc0[tile] = (f32x4){0.f,0.f,0.f,0.f};
        acc1[tile] = (f32x4){0.f,0.f,0.f,0.f};
    }

    {
        const short8v af = cvt8(a00, a01);           // rt0, k 0..31
        #pragma unroll
        for (int tile = 0; tile < 8; ++tile)
            acc0[tile] = __builtin_amdgcn_mfma_f32_16x16x32_bf16(wfrag[tile][0], af, acc0[tile], 0, 0, 0);
    }
    {
        const short8v af = cvt8(a02, a03);           // rt0, k 32..63
        #pragma unroll
        for (int tile = 0; tile < 8; ++tile)
            acc0[tile] = __builtin_amdgcn_mfma_f32_16x16x32_bf16(wfrag[tile][1], af, acc0[tile], 0, 0, 0);
    }
    {
        const short8v af = cvt8(a10, a11);           // rt1, k 0..31
        #pragma unroll
        for (int tile = 0; tile < 8; ++tile)
            acc1[tile] = __builtin_amdgcn_mfma_f32_16x16x32_bf16(wfrag[tile][0], af, acc1[tile], 0, 0, 0);
    }
    {
        const short8v af = cvt8(a12, a13);           // rt1, k 32..63
        #pragma unroll
        for (int tile = 0; tile < 8; ++tile)
            acc1[tile] = __builtin_amdgcn_mfma_f32_16x16x32_bf16(wfrag[tile][1], af, acc1[tile], 0, 0, 0);
    }

    // Epilogue per row-tile: lane owns X-row gR, channels tile*16 + q*4 + reg.
    // Slot index vv = b*192 + tt*16 + tf*4 + q; 8-B slot in chunk (vv>>6, n).
    #pragma unroll
    for (int rt = 0; rt < 2; ++rt) {
        const int gR = rt ? gR1 : gR0;
        const f32x4* acc = rt ? acc1 : acc0;
        const int b  = gR / NT_;
        const int rm = gR - b*NT_;
        const int n  = rm / T_;
        const int tt = rm - n*T_;
        const int vbase = b*192 + tt*16;
        #pragma unroll
        for (int tf = 0; tf < 4; ++tf) {
            const int d0 = tf*16 + q*4;
            const float4 bm4 = *(const float4*)&bm[d0];
            const float4 bp4 = *(const float4*)&bpp[d0];
            const float f0 = acc[tf][0] + bm4.x;
            const float f1 = acc[tf][1] + bm4.y;
            const float f2 = acc[tf][2] + bm4.z;
            const float f3 = acc[tf][3] + bm4.w;
            const float p0 = __builtin_amdgcn_exp2f(acc[tf+4][0] + bp4.x);
            const float p1 = __builtin_amdgcn_exp2f(acc[tf+4][1] + bp4.y);
            const float p2 = __builtin_amdgcn_exp2f(acc[tf+4][2] + bp4.z);
            const float p3 = __builtin_amdgcn_exp2f(acc[tf+4][3] + bp4.w);
            int fw = __builtin_amdgcn_cvt_pk_fp8_f32(f0, f1, 0, false);
            fw     = __builtin_amdgcn_cvt_pk_fp8_f32(f2, f3, fw, true);
            int pw = __builtin_amdgcn_cvt_pk_fp8_f32(p0, p1, 0, false);
            pw     = __builtin_amdgcn_cvt_pk_fp8_f32(p2, p3, pw, true);
            const int vv = vbase + tf*4 + q;
            char* slot = packed + ((size_t)(vv >> 6)*2000 + n)*CHUNKB_ + (size_t)(vv & 63)*SLOTB_;
            uint2 u2; u2.x = (uint32_t)fw; u2.y = (uint32_t)pw;
            *(uint2*)slot = u2;
        }
    }
}

// ---------- Kernel 2: per-node 8-edge softmax aggregation, K graphs ----------
// R19 version, unchanged. MEASUREMENT ROUND: launched TWICE (idempotent —
// fully overwrites out from packed/input/edges/weight) so the replay-total
// delta vs R19's 46.2 µs equals gcn's true replay duration.
__launch_bounds__(128, 4)
__global__ void gcn_kernel(const char* __restrict__ packed,
                           const float* __restrict__ input,
                           const int* __restrict__ edges,
                           const float* __restrict__ weight,
                           float* __restrict__ out) {
    const uint32_t wgid = blockIdx.x;          // [0,12000)
    const uint32_t xcd  = wgid & 7;            // assumed XCD id (round-robin)
    const uint32_t slot = wgid >> 3;           // [0,1500) within XCD
    const uint32_t vw   = xcd * 1500u + slot;  // phase-major virtual work item
    const int ss   = (int)(vw / 1000u);        // phase [0,12)
    const int pair = (int)(vw - (uint32_t)ss * 1000u);   // [0,1000)

    const int wv = __builtin_amdgcn_readfirstlane(threadIdx.x >> 6);  // wave 0/1
    const int n  = pair*2 + wv;
    const int t  = threadIdx.x & 63;      // lane

    const int vv = ss*64 + t;             // 4-channel group index [0,768)
    const int b  = vv / V4PB_;
    const int r4 = vv - b*V4PB_;
    const size_t off4 = (size_t)b*(NT_*D_/4) + (size_t)n*V4PB_ + r4;

    // Wave-uniform edge indices (SGPR) for all 3 graphs.
    int srcs[24];
    #pragma unroll
    for (int k = 0; k < K_; ++k) {
        const int4 e0 = *(const int4*)(edges + (size_t)k*(2*E_) + n*DEG_);
        const int4 e1 = *(const int4*)(edges + (size_t)k*(2*E_) + n*DEG_ + 4);
        srcs[k*8+0]=e0.x; srcs[k*8+1]=e0.y; srcs[k*8+2]=e0.z; srcs[k*8+3]=e0.w;
        srcs[k*8+4]=e1.x; srcs[k*8+5]=e1.y; srcs[k*8+6]=e1.z; srcs[k*8+7]=e1.w;
    }

    // Issue residual + ALL 24 gathers, then pin with sched_barrier(0).
    const float4 inv = ((const float4*)input)[off4];
    const char* pbase = packed + (size_t)((uint32_t)(ss*2000))*CHUNKB_ + (size_t)t*SLOTB_;
#define GLOAD(i) const uint2 g##i = *(const uint2*)(pbase + (size_t)(uint32_t)srcs[i]*CHUNKB_)
    GLOAD(0);  GLOAD(1);  GLOAD(2);  GLOAD(3);  GLOAD(4);  GLOAD(5);
    GLOAD(6);  GLOAD(7);  GLOAD(8);  GLOAD(9);  GLOAD(10); GLOAD(11);
    GLOAD(12); GLOAD(13); GLOAD(14); GLOAD(15); GLOAD(16); GLOAD(17);
    GLOAD(18); GLOAD(19); GLOAD(20); GLOAD(21); GLOAD(22); GLOAD(23);
#undef GLOAD
    __builtin_amdgcn_sched_barrier(0);

    const uint2 g[24] = {g0,g1,g2,g3,g4,g5,g6,g7,g8,g9,g10,g11,
                         g12,g13,g14,g15,g16,g17,g18,g19,g20,g21,g22,g23};

    float acc[4] = {0.f, 0.f, 0.f, 0.f};
    #pragma unroll
    for (int k = 0; k < K_; ++k) {
        const float wk = weight[k];
        float s0=0.f,s1=0.f,s2=0.f,s3=0.f;
        float n0=0.f,n1=0.f,n2=0.f,n3=0.f;
        #pragma unroll
        for (int j = 0; j < 8; ++j) {
            const uint2 gv = g[k*8 + j];                 // static index (unrolled)
            const f32x2 fA = __builtin_amdgcn_cvt_pk_f32_fp8((int)gv.x, false); // f0,f1
            const f32x2 fB = __builtin_amdgcn_cvt_pk_f32_fp8((int)gv.x, true);  // f2,f3
            const f32x2 pA = __builtin_amdgcn_cvt_pk_f32_fp8((int)gv.y, false); // p0,p1
            const f32x2 pB = __builtin_amdgcn_cvt_pk_f32_fp8((int)gv.y, true);  // p2,p3
            s0 += pA[0]; n0 = fmaf(pA[0], fA[0], n0);
            s1 += pA[1]; n1 = fmaf(pA[1], fA[1], n1);
            s2 += pB[0]; n2 = fmaf(pB[0], fB[0], n2);
            s3 += pB[1]; n3 = fmaf(pB[1], fB[1], n3);
        }
        acc[0] += wk * n0 * __builtin_amdgcn_rcpf(s0);
        acc[1] += wk * n1 * __builtin_amdgcn_rcpf(s1);
        acc[2] += wk * n2 * __builtin_amdgcn_rcpf(s2);
        acc[3] += wk * n3 * __builtin_amdgcn_rcpf(s3);
    }

    float4 o;
    o.x = (acc[0] > 0.f ? acc[0] : 0.01f*acc[0]) + inv.x;
    o.y = (acc[1] > 0.f ? acc[1] : 0.01f*acc[1]) + inv.y;
    o.z = (acc[2] > 0.f ? acc[2] : 0.01f*acc[2]) + inv.z;
    o.w = (acc[3] > 0.f ? acc[3] : 0.01f*acc[3]) + inv.w;
    ((float4*)out)[off4] = o;
}

extern "C" void kernel_launch(void* const* d_in, const int* in_sizes, int n_in,
                              void* d_out, int out_size, void* d_ws, size_t ws_size,
                              hipStream_t stream) {
    const float* input  = (const float*)d_in[0];
    const float* Wm     = (const float*)d_in[1];
    const float* bm     = (const float*)d_in[2];
    const float* Wa     = (const float*)d_in[3];
    // d_in[4] = b_attn (cancels inside per-dst softmax), unused
    const float* weight = (const float*)d_in[5];
    const int*   edges  = (const int*)d_in[6];
    float* out = (float*)d_out;
    char* packed = (char*)d_ws;   // phase-major: chunk (ss*2000+n) of 512 B

    // Prep scratch lives in the head of d_out; gcn_kernel fully overwrites out.
    uint16_t* WBf = (uint16_t*)d_out;             // 16 fragment-slots x 64 lanes x 16 B = 16 KB
    float*    bpp = (float*)d_out + 4096;         // 64 floats

    hipLaunchKernelGGL(prep_kernel, dim3(17), dim3(64), 0, stream, Wm, Wa, bm, WBf, bpp);
    hipLaunchKernelGGL(mlp_mfma, dim3(ROWS_/128), dim3(256), 0, stream,
                       input, WBf, bm, bpp, packed);
    // MEASUREMENT: gcn launched twice (idempotent). Replay-total delta vs
    // R19's 46.2 µs = gcn's true replay duration.
    hipLaunchKernelGGL(gcn_kernel, dim3(12000), dim3(128), 0, stream,
                       packed, input, edges, weight, out);
    hipLaunchKernelGGL(gcn_kernel, dim3(12000), dim3(128), 0, stream,
                       packed, input, edges, weight, out);
}

// Round 21
// 43.794 us; speedup vs baseline: 1.5185x; 1.5185x over previous
//
#include <hip/hip_runtime.h>
#include <hip/hip_bf16.h>
#include <stdint.h>

#define B_ 4
#define N_ 2000
#define T_ 12
#define D_ 64
#define K_ 3
#define DEG_ 8
#define E_ (N_*DEG_)              // 16000
#define ROWS_ (B_*N_*T_)          // 96000
#define NT_ (N_*T_)               // 24000
#define V4PB_ (T_*D_/4)           // 192 4-channel groups per (node,b)
#define SLOTB_ 8                  // bytes per 4-channel group: f0..f3 e4m3 + p0..p3 e4m3
#define CHUNKB_ (64*SLOTB_)       // 512 B per (phase, node) chunk
#define CHUNKROW_ ((size_t)2000*CHUNKB_)  // 1,024,000 B per phase row
#define LOG2E_ 1.4426950408889634f

typedef __attribute__((ext_vector_type(8))) short short8v;   // 8 bf16 = 4 VGPR
typedef __attribute__((ext_vector_type(4))) float f32x4;     // MFMA acc
typedef __attribute__((ext_vector_type(2))) float f32x2;     // fp8 cvt result

__device__ __forceinline__ uint32_t f32_to_bf16_bits(float x) {
    uint32_t u = __float_as_uint(x);
    return (u + 0x7FFFu + ((u >> 16) & 1u)) >> 16;   // RNE
}
__device__ __forceinline__ short8v cvt8(float4 lo, float4 hi) {
    short8v af;
    af[0] = (short)f32_to_bf16_bits(lo.x);
    af[1] = (short)f32_to_bf16_bits(lo.y);
    af[2] = (short)f32_to_bf16_bits(lo.z);
    af[3] = (short)f32_to_bf16_bits(lo.w);
    af[4] = (short)f32_to_bf16_bits(hi.x);
    af[5] = (short)f32_to_bf16_bits(hi.y);
    af[6] = (short)f32_to_bf16_bits(hi.z);
    af[7] = (short)f32_to_bf16_bits(hi.w);
    return af;
}

// ---------- Kernel 0 (prep): fragment-linear W table + bias ----------
// (unchanged from R19 — measured ~2 µs incl. dispatch)
__global__ void prep_kernel(const float* __restrict__ Wm,
                            const float* __restrict__ Wa,
                            const float* __restrict__ bm,
                            uint16_t* __restrict__ WBf,
                            float* __restrict__ bpp) {
    const int blk  = blockIdx.x;          // 0..16
    const int lane = threadIdx.x;         // 64
    if (blk < 16) {
        const int tile = blk >> 1, s = blk & 1;
        const int r = lane & 15, q = lane >> 4;
        const int c = tile*16 + r;
        uint16_t o[8];
        #pragma unroll
        for (int e = 0; e < 8; ++e) {
            const int k = s*32 + q*8 + e;
            float v;
            if (c < 64) {
                v = Wm[k*64 + c];
            } else {
                v = 0.f;
                #pragma unroll
                for (int j = 0; j < 64; ++j) v += Wm[k*64 + j] * Wa[j*64 + (c - 64)];
                v *= LOG2E_;
            }
            o[e] = (uint16_t)f32_to_bf16_bits(v);
        }
        *(uint4*)(WBf + (size_t)(blk*64 + lane)*8) = *(const uint4*)o;
    } else {
        float s = 0.f;
        #pragma unroll
        for (int e = 0; e < 64; ++e) s += bm[e] * Wa[e*64 + lane];
        bpp[lane] = s * LOG2E_;
    }
}

// ---------- Kernel 1: MFMA GEMM [96000x64]@[64x128] -> pack (f fp8, p fp8) ----------
// (unchanged from R19 — measured ~11.3 µs, near HBM floor)
__launch_bounds__(256)
__global__ void mlp_mfma(const float* __restrict__ X,
                         const uint16_t* __restrict__ WBf,
                         const float* __restrict__ bm,
                         const float* __restrict__ bpp,
                         char* __restrict__ packed) {
    const int t    = threadIdx.x;
    const int wave = t >> 6, lane = t & 63;
    const int r    = lane & 15, q = lane >> 4;

    const int row0 = blockIdx.x*128 + wave*32;
    const int gR0  = row0 + r;            // row-tile 0
    const int gR1  = row0 + 16 + r;       // row-tile 1

    const float* xp0 = X + (size_t)gR0*64 + q*8;
    const float* xp1 = X + (size_t)gR1*64 + q*8;
    const float4 a00 = *(const float4*)(xp0);
    const float4 a01 = *(const float4*)(xp0 + 4);
    const float4 a02 = *(const float4*)(xp0 + 32);
    const float4 a03 = *(const float4*)(xp0 + 36);
    const float4 a10 = *(const float4*)(xp1);
    const float4 a11 = *(const float4*)(xp1 + 4);
    const float4 a12 = *(const float4*)(xp1 + 32);
    const float4 a13 = *(const float4*)(xp1 + 36);

    short8v wfrag[8][2];
    #pragma unroll
    for (int tile = 0; tile < 8; ++tile)
        #pragma unroll
        for (int s = 0; s < 2; ++s)
            wfrag[tile][s] = *(const short8v*)(WBf + (size_t)((tile*2+s)*64 + lane)*8);

    f32x4 acc0[8], acc1[8];
    #pragma unroll
    for (int tile = 0; tile < 8; ++tile) {
        acc0[tile] = (f32x4){0.f,0.f,0.f,0.f};
        acc1[tile] = (f32x4){0.f,0.f,0.f,0.f};
    }

    {
        const short8v af = cvt8(a00, a01);           // rt0, k 0..31
        #pragma unroll
        for (int tile = 0; tile < 8; ++tile)
            acc0[tile] = __builtin_amdgcn_mfma_f32_16x16x32_bf16(wfrag[tile][0], af, acc0[tile], 0, 0, 0);
    }
    {
        const short8v af = cvt8(a02, a03);           // rt0, k 32..63
        #pragma unroll
        for (int tile = 0; tile < 8; ++tile)
            acc0[tile] = __builtin_amdgcn_mfma_f32_16x16x32_bf16(wfrag[tile][1], af, acc0[tile], 0, 0, 0);
    }
    {
        const short8v af = cvt8(a10, a11);           // rt1, k 0..31
        #pragma unroll
        for (int tile = 0; tile < 8; ++tile)
            acc1[tile] = __builtin_amdgcn_mfma_f32_16x16x32_bf16(wfrag[tile][0], af, acc1[tile], 0, 0, 0);
    }
    {
        const short8v af = cvt8(a12, a13);           // rt1, k 32..63
        #pragma unroll
        for (int tile = 0; tile < 8; ++tile)
            acc1[tile] = __builtin_amdgcn_mfma_f32_16x16x32_bf16(wfrag[tile][1], af, acc1[tile], 0, 0, 0);
    }

    #pragma unroll
    for (int rt = 0; rt < 2; ++rt) {
        const int gR = rt ? gR1 : gR0;
        const f32x4* acc = rt ? acc1 : acc0;
        const int b  = gR / NT_;
        const int rm = gR - b*NT_;
        const int n  = rm / T_;
        const int tt = rm - n*T_;
        const int vbase = b*192 + tt*16;
        #pragma unroll
        for (int tf = 0; tf < 4; ++tf) {
            const int d0 = tf*16 + q*4;
            const float4 bm4 = *(const float4*)&bm[d0];
            const float4 bp4 = *(const float4*)&bpp[d0];
            const float f0 = acc[tf][0] + bm4.x;
            const float f1 = acc[tf][1] + bm4.y;
            const float f2 = acc[tf][2] + bm4.z;
            const float f3 = acc[tf][3] + bm4.w;
            const float p0 = __builtin_amdgcn_exp2f(acc[tf+4][0] + bp4.x);
            const float p1 = __builtin_amdgcn_exp2f(acc[tf+4][1] + bp4.y);
            const float p2 = __builtin_amdgcn_exp2f(acc[tf+4][2] + bp4.z);
            const float p3 = __builtin_amdgcn_exp2f(acc[tf+4][3] + bp4.w);
            int fw = __builtin_amdgcn_cvt_pk_fp8_f32(f0, f1, 0, false);
            fw     = __builtin_amdgcn_cvt_pk_fp8_f32(f2, f3, fw, true);
            int pw = __builtin_amdgcn_cvt_pk_fp8_f32(p0, p1, 0, false);
            pw     = __builtin_amdgcn_cvt_pk_fp8_f32(p2, p3, pw, true);
            const int vv = vbase + tf*4 + q;
            char* slot = packed + ((size_t)(vv >> 6)*2000 + n)*CHUNKB_ + (size_t)(vv & 63)*SLOTB_;
            uint2 u2; u2.x = (uint32_t)fw; u2.y = (uint32_t)pw;
            *(uint2*)slot = u2;
        }
    }
}

// ---------- Kernel 2: per-node 8-edge softmax aggregation, K graphs ----------
// RE-TILE (R21): each lane loads 16 B (uint4 = 2 adjacent 8-B slots); a wave
// covers a DOUBLE phase (lanes 0-31 -> phase 2*ss2, lanes 32-63 -> 2*ss2+1;
// two 512-B contiguous segments per gather). Gather instruction count and
// wave count both halve at constant cache-line count; per-wave fixed costs
// (edge s_loads, addr setup) amortize 2x. Grid 6000 blocks x 128 threads.
// Packed layout identical to R19 -> bit-identical output.
__launch_bounds__(128, 3)
__global__ void gcn_kernel(const char* __restrict__ packed,
                           const float* __restrict__ input,
                           const int* __restrict__ edges,
                           const float* __restrict__ weight,
                           float* __restrict__ out) {
    const uint32_t wgid = blockIdx.x;          // [0,6000)
    const uint32_t xcd  = wgid & 7;            // assumed XCD id (round-robin)
    const uint32_t slot = wgid >> 3;           // [0,750) within XCD
    const uint32_t vw   = xcd * 750u + slot;   // phase-major virtual work item
    const int ss2  = (int)(vw / 1000u);        // double-phase [0,6)
    const int pair = (int)(vw - (uint32_t)ss2 * 1000u);  // [0,1000)

    const int wv = __builtin_amdgcn_readfirstlane(threadIdx.x >> 6);  // wave 0/1
    const int n  = pair*2 + wv;
    const int t  = threadIdx.x & 63;      // lane

    const int vv = ss2*128 + 2*t;         // even 4-group index [0,768)
    const int b  = vv / V4PB_;            // pair (vv,vv+1) never straddles b
    const int r4 = vv - b*V4PB_;
    const size_t off4 = (size_t)b*(NT_*D_/4) + (size_t)n*V4PB_ + r4;

    // Wave-uniform edge indices (SGPR) for all 3 graphs.
    int srcs[24];
    #pragma unroll
    for (int k = 0; k < K_; ++k) {
        const int4 e0 = *(const int4*)(edges + (size_t)k*(2*E_) + n*DEG_);
        const int4 e1 = *(const int4*)(edges + (size_t)k*(2*E_) + n*DEG_ + 4);
        srcs[k*8+0]=e0.x; srcs[k*8+1]=e0.y; srcs[k*8+2]=e0.z; srcs[k*8+3]=e0.w;
        srcs[k*8+4]=e1.x; srcs[k*8+5]=e1.y; srcs[k*8+6]=e1.z; srcs[k*8+7]=e1.w;
    }

    // Issue residual (2x float4) + ALL 24 gathers (uint4), pin with sched_barrier.
    const float4 inv0 = ((const float4*)input)[off4];
    const float4 inv1 = ((const float4*)input)[off4 + 1];
    // lane base: phase row (2*ss2 + t>>5), slot byte (t&31)*16 within chunk
    const char* pbase = packed + (size_t)(2*ss2 + (t >> 5))*CHUNKROW_ + (size_t)(t & 31)*16;
#define GLOAD(i) const uint4 g##i = *(const uint4*)(pbase + (size_t)(uint32_t)srcs[i]*CHUNKB_)
    GLOAD(0);  GLOAD(1);  GLOAD(2);  GLOAD(3);  GLOAD(4);  GLOAD(5);
    GLOAD(6);  GLOAD(7);  GLOAD(8);  GLOAD(9);  GLOAD(10); GLOAD(11);
    GLOAD(12); GLOAD(13); GLOAD(14); GLOAD(15); GLOAD(16); GLOAD(17);
    GLOAD(18); GLOAD(19); GLOAD(20); GLOAD(21); GLOAD(22); GLOAD(23);
#undef GLOAD
    __builtin_amdgcn_sched_barrier(0);

    const uint4 g[24] = {g0,g1,g2,g3,g4,g5,g6,g7,g8,g9,g10,g11,
                         g12,g13,g14,g15,g16,g17,g18,g19,g20,g21,g22,g23};

    float acc[8] = {0.f,0.f,0.f,0.f,0.f,0.f,0.f,0.f};
    #pragma unroll
    for (int k = 0; k < K_; ++k) {
        const float wk = weight[k];
        float s[8] = {0.f,0.f,0.f,0.f,0.f,0.f,0.f,0.f};
        float m[8] = {0.f,0.f,0.f,0.f,0.f,0.f,0.f,0.f};
        #pragma unroll
        for (int j = 0; j < 8; ++j) {
            const uint4 gv = g[k*8 + j];                 // static index (unrolled)
            // group A = slot vv   (gv.x=f, gv.y=p); group B = slot vv+1 (gv.z, gv.w)
            const f32x2 fA0 = __builtin_amdgcn_cvt_pk_f32_fp8((int)gv.x, false);
            const f32x2 fA1 = __builtin_amdgcn_cvt_pk_f32_fp8((int)gv.x, true);
            const f32x2 pA0 = __builtin_amdgcn_cvt_pk_f32_fp8((int)gv.y, false);
            const f32x2 pA1 = __builtin_amdgcn_cvt_pk_f32_fp8((int)gv.y, true);
            const f32x2 fB0 = __builtin_amdgcn_cvt_pk_f32_fp8((int)gv.z, false);
            const f32x2 fB1 = __builtin_amdgcn_cvt_pk_f32_fp8((int)gv.z, true);
            const f32x2 pB0 = __builtin_amdgcn_cvt_pk_f32_fp8((int)gv.w, false);
            const f32x2 pB1 = __builtin_amdgcn_cvt_pk_f32_fp8((int)gv.w, true);
            s[0] += pA0[0]; m[0] = fmaf(pA0[0], fA0[0], m[0]);
            s[1] += pA0[1]; m[1] = fmaf(pA0[1], fA0[1], m[1]);
            s[2] += pA1[0]; m[2] = fmaf(pA1[0], fA1[0], m[2]);
            s[3] += pA1[1]; m[3] = fmaf(pA1[1], fA1[1], m[3]);
            s[4] += pB0[0]; m[4] = fmaf(pB0[0], fB0[0], m[4]);
            s[5] += pB0[1]; m[5] = fmaf(pB0[1], fB0[1], m[5]);
            s[6] += pB1[0]; m[6] = fmaf(pB1[0], fB1[0], m[6]);
            s[7] += pB1[1]; m[7] = fmaf(pB1[1], fB1[1], m[7]);
        }
        #pragma unroll
        for (int c = 0; c < 8; ++c)
            acc[c] += wk * m[c] * __builtin_amdgcn_rcpf(s[c]);
    }

    float4 o0, o1;
    o0.x = (acc[0] > 0.f ? acc[0] : 0.01f*acc[0]) + inv0.x;
    o0.y = (acc[1] > 0.f ? acc[1] : 0.01f*acc[1]) + inv0.y;
    o0.z = (acc[2] > 0.f ? acc[2] : 0.01f*acc[2]) + inv0.z;
    o0.w = (acc[3] > 0.f ? acc[3] : 0.01f*acc[3]) + inv0.w;
    o1.x = (acc[4] > 0.f ? acc[4] : 0.01f*acc[4]) + inv1.x;
    o1.y = (acc[5] > 0.f ? acc[5] : 0.01f*acc[5]) + inv1.y;
    o1.z = (acc[6] > 0.f ? acc[6] : 0.01f*acc[6]) + inv1.z;
    o1.w = (acc[7] > 0.f ? acc[7] : 0.01f*acc[7]) + inv1.w;
    ((float4*)out)[off4]     = o0;
    ((float4*)out)[off4 + 1] = o1;
}

extern "C" void kernel_launch(void* const* d_in, const int* in_sizes, int n_in,
                              void* d_out, int out_size, void* d_ws, size_t ws_size,
                              hipStream_t stream) {
    const float* input  = (const float*)d_in[0];
    const float* Wm     = (const float*)d_in[1];
    const float* bm     = (const float*)d_in[2];
    const float* Wa     = (const float*)d_in[3];
    // d_in[4] = b_attn (cancels inside per-dst softmax), unused
    const float* weight = (const float*)d_in[5];
    const int*   edges  = (const int*)d_in[6];
    float* out = (float*)d_out;
    char* packed = (char*)d_ws;   // phase-major: chunk (ss*2000+n) of 512 B

    // Prep scratch lives in the head of d_out; gcn_kernel fully overwrites out.
    uint16_t* WBf = (uint16_t*)d_out;             // 16 fragment-slots x 64 lanes x 16 B = 16 KB
    float*    bpp = (float*)d_out + 4096;         // 64 floats

    hipLaunchKernelGGL(prep_kernel, dim3(17), dim3(64), 0, stream, Wm, Wa, bm, WBf, bpp);
    hipLaunchKernelGGL(mlp_mfma, dim3(ROWS_/128), dim3(256), 0, stream,
                       input, WBf, bm, bpp, packed);
    hipLaunchKernelGGL(gcn_kernel, dim3(6000), dim3(128), 0, stream,
                       packed, input, edges, weight, out);
}